// Round 5
// baseline (678.259 us; speedup 1.0000x reference)
//
#include <hip/hip_runtime.h>

namespace {

constexpr int TT = 1024;   // timesteps
constexpr int NB = 4096;   // batch
constexpr int H0 = 15, H1 = 10, H2 = 2;

// Pre-scales so activations use v_exp_f32 (exp2) directly:
// sigmoid(v) = 1/(1+exp2(-v*L2E)); tanh(u) = 2/(1+exp2(-u*2*L2E)) - 1.
constexpr float L2E  = 1.44269504088896340736f;
constexpr float L2E2 = 2.88539008177792681472f;

// Staging vector per sample (floats): x[0..4] pad[5..7] h0[8..22] pad[23]
// h1[24..33] pad[34..35] h2[36..37] pad[38..47].  Window starts (16B-aligned):
// L0 -> 0 (x+h0), L1 -> 8 (h0+h1), L2 -> 24 (h1+h2). Window = 28 floats.
constexpr int SSTRIDE = 48;

typedef float v2f __attribute__((ext_vector_type(2)));
typedef float v4f __attribute__((ext_vector_type(4)));

__device__ __forceinline__ float frcp(float v)  { return __builtin_amdgcn_rcpf(v); }
__device__ __forceinline__ float fexp2(float v) { return __builtin_amdgcn_exp2f(v); }
__device__ __forceinline__ float sigm_p(float v) { return frcp(1.0f + fexp2(-v)); }
__device__ __forceinline__ float tanh_p(float u) {
  return __builtin_fmaf(2.0f, frcp(1.0f + fexp2(-u)), -1.0f);
}

// In-place packed FMA: acc = a*b + acc (ONE v_pk_fma_f32, accumulator tied
// via "+v" so no register-copy movs — R4's "=v" form cost 2 movs per op).
__device__ __forceinline__ void pk_fma(v2f& acc, v2f a, v2f b) {
  asm("v_pk_fma_f32 %0, %1, %2, %0" : "+v"(acc) : "v"(a), "v"(b));
}

}  // namespace

// Grid: 2048 blocks x 64 threads = 2 waves/SIMD. Wave = 2 samples x 32 lanes.
// Per sample: lanes 0-14 = L0 units, 15-24 = L1 units, 25-26 = L2 units,
// 27-31 = x-loaders. Uniform code: every lane reads a 28-float window of
// [x|h0|h1|h2] staging and does 4 zero-padded dots as 56 v_pk_fma_f32.
// Layers skewed (iter i: L0(i), L1(i-1), L2(i-2)) -> one publish/iteration.
// Single-wave block: no __syncthreads (wave-lockstep + in-order DS pipe);
// wave_barrier pins compiler ordering.
extern "C" __global__ __launch_bounds__(64, 2) void gru3_fused(
    const float* __restrict__ x,
    const float* __restrict__ w_ih0, const float* __restrict__ w_hh0,
    const float* __restrict__ b_ih0, const float* __restrict__ b_hh0,
    const float* __restrict__ w_ih1, const float* __restrict__ w_hh1,
    const float* __restrict__ b_ih1, const float* __restrict__ b_hh1,
    const float* __restrict__ w_ih2, const float* __restrict__ w_hh2,
    const float* __restrict__ b_ih2, const float* __restrict__ b_hh2,
    float* __restrict__ out) {
  // 2 samples * 48 + tail pad so L2's window over-read stays in-buffer.
  __shared__ __attribute__((aligned(16))) float stage[112];

  const int tid  = threadIdx.x;
  const int lane = tid & 31;
  const int smp  = tid >> 5;
  const int b    = blockIdx.x * 2 + smp;
  const int sbase = smp * SSTRIDE;

  int cls, u;
  if (lane < 15)      { cls = 0; u = lane; }
  else if (lane < 25) { cls = 1; u = lane - 15; }
  else if (lane < 27) { cls = 2; u = lane - 25; }
  else                { cls = 3; u = lane - 27; }   // x-loader

  const int  woff   = (cls == 0) ? 0 : (cls == 1) ? 8 : (cls == 2) ? 24 : 0;
  const int  wpos   = (cls == 0) ? 8 + u : (cls == 1) ? 24 + u
                    : (cls == 2) ? 36 + u : u;
  const int  istart = cls;            // suppress h-update until layer's first step
  const bool is_x   = (cls == 3);
  const bool is_o   = (cls == 2);
  const int  xj     = is_x ? u : 0;   // in-bounds x column for everyone

  // ---- per-lane padded weight vectors (zero outside class's inputs) ----
  float Wr[28], Wz[28], Wnx[28], Wnh[28];
#pragma unroll
  for (int j = 0; j < 28; ++j) { Wr[j] = 0.f; Wz[j] = 0.f; Wnx[j] = 0.f; Wnh[j] = 0.f; }
  float br = 0.f, bz = 0.f, bnx = 0.f, bnh = 0.f;

  if (cls == 0) {
#pragma unroll
    for (int j = 0; j < 5; ++j) {
      Wr [j] = w_ih0[(u         ) * 5 + j] * L2E;
      Wz [j] = w_ih0[(H0 + u    ) * 5 + j] * L2E;
      Wnx[j] = w_ih0[(2 * H0 + u) * 5 + j] * L2E2;
    }
#pragma unroll
    for (int k = 0; k < 15; ++k) {
      Wr [8 + k] = w_hh0[(u         ) * 15 + k] * L2E;
      Wz [8 + k] = w_hh0[(H0 + u    ) * 15 + k] * L2E;
      Wnh[8 + k] = w_hh0[(2 * H0 + u) * 15 + k] * L2E2;
    }
    br  = (b_ih0[u] + b_hh0[u]) * L2E;
    bz  = (b_ih0[H0 + u] + b_hh0[H0 + u]) * L2E;
    bnx = b_ih0[2 * H0 + u] * L2E2;
    bnh = b_hh0[2 * H0 + u] * L2E2;
  } else if (cls == 1) {
#pragma unroll
    for (int k = 0; k < 15; ++k) {
      Wr [k] = w_ih1[(u         ) * 15 + k] * L2E;
      Wz [k] = w_ih1[(H1 + u    ) * 15 + k] * L2E;
      Wnx[k] = w_ih1[(2 * H1 + u) * 15 + k] * L2E2;
    }
#pragma unroll
    for (int k = 0; k < 10; ++k) {
      Wr [16 + k] = w_hh1[(u         ) * 10 + k] * L2E;
      Wz [16 + k] = w_hh1[(H1 + u    ) * 10 + k] * L2E;
      Wnh[16 + k] = w_hh1[(2 * H1 + u) * 10 + k] * L2E2;
    }
    br  = (b_ih1[u] + b_hh1[u]) * L2E;
    bz  = (b_ih1[H1 + u] + b_hh1[H1 + u]) * L2E;
    bnx = b_ih1[2 * H1 + u] * L2E2;
    bnh = b_hh1[2 * H1 + u] * L2E2;
  } else if (cls == 2) {
#pragma unroll
    for (int k = 0; k < 10; ++k) {
      Wr [k] = w_ih2[(u         ) * 10 + k] * L2E;
      Wz [k] = w_ih2[(H2 + u    ) * 10 + k] * L2E;
      Wnx[k] = w_ih2[(2 * H2 + u) * 10 + k] * L2E2;
    }
#pragma unroll
    for (int k = 0; k < 2; ++k) {
      Wr [12 + k] = w_hh2[(u         ) * 2 + k] * L2E;
      Wz [12 + k] = w_hh2[(H2 + u    ) * 2 + k] * L2E;
      Wnh[12 + k] = w_hh2[(2 * H2 + u) * 2 + k] * L2E2;
    }
    br  = (b_ih2[u] + b_hh2[u]) * L2E;
    bz  = (b_ih2[H2 + u] + b_hh2[H2 + u]) * L2E;
    bnx = b_ih2[2 * H2 + u] * L2E2;
    bnh = b_hh2[2 * H2 + u] * L2E2;
  }

  // pack to float2 for v_pk_fma_f32
  v2f Wr2[14], Wz2[14], Wnx2[14], Wnh2[14];
#pragma unroll
  for (int j = 0; j < 14; ++j) {
    Wr2 [j] = (v2f){Wr [2 * j], Wr [2 * j + 1]};
    Wz2 [j] = (v2f){Wz [2 * j], Wz [2 * j + 1]};
    Wnx2[j] = (v2f){Wnx[2 * j], Wnx[2 * j + 1]};
    Wnh2[j] = (v2f){Wnh[2 * j], Wnh[2 * j + 1]};
  }

  // ---- init staging (zeros = h(-1) states + pads), publish x(0) ----
  for (int j = tid; j < 112; j += 64) stage[j] = 0.0f;

  float xw, xn;   // x publish pipeline: xw = x(i+1), xn = x(i+2)
  {
    const int base = b * 5 + xj;
    const float x0 = x[base];                 // t=0
    xw = x[NB * 5 + base];                    // t=1
    xn = x[2 * NB * 5 + base];                // t=2
    if (is_x) stage[sbase + u] = x0;
  }
  __builtin_amdgcn_wave_barrier();

  float h = 0.0f;
  const v4f* wloc = (const v4f*)&stage[sbase + woff];
  float* pub = &stage[sbase + wpos];

  // Strength-reduced pointers: x prefetch (x(i+3), clamped) and out store.
  const float* xp = x + ((size_t)3 * NB + b) * 5 + xj;
  const size_t xstep = (size_t)NB * 5;
  float* op = out + (size_t)b * H2 + (is_o ? u : 0);  // t = i-2 target
  const size_t ostep = (size_t)NB * H2;

#pragma unroll 1
  for (int i = 0; i <= TT + 1; ++i) {
    // window read (sees previous iteration's publishes; in-order DS pipe)
    const v4f q0 = wloc[0], q1 = wloc[1], q2 = wloc[2], q3 = wloc[3];
    const v4f q4 = wloc[4], q5 = wloc[5], q6 = wloc[6];

    // prefetch x(i+3) (uniform-issue; only x-lanes consume)
    const float xldv = *xp;
    if (i + 4 < TT) xp += xstep;    // uniform scalar condition

    v2f aR  = (v2f){br,  0.f};
    v2f aZ  = (v2f){bz,  0.f};
    v2f aNx = (v2f){bnx, 0.f};
    v2f aNh = (v2f){bnh, 0.f};
#define GRU_DOT2(J, QH)           \
    pk_fma(aR,  Wr2 [J], (QH));   \
    pk_fma(aZ,  Wz2 [J], (QH));   \
    pk_fma(aNx, Wnx2[J], (QH));   \
    pk_fma(aNh, Wnh2[J], (QH));
    GRU_DOT2(0,  q0.lo)
    GRU_DOT2(1,  q0.hi)
    GRU_DOT2(2,  q1.lo)
    GRU_DOT2(3,  q1.hi)
    GRU_DOT2(4,  q2.lo)
    GRU_DOT2(5,  q2.hi)
    GRU_DOT2(6,  q3.lo)
    GRU_DOT2(7,  q3.hi)
    GRU_DOT2(8,  q4.lo)
    GRU_DOT2(9,  q4.hi)
    GRU_DOT2(10, q5.lo)
    GRU_DOT2(11, q5.hi)
    GRU_DOT2(12, q6.lo)
    GRU_DOT2(13, q6.hi)
#undef GRU_DOT2

    const float r = sigm_p(aR.x + aR.y);
    const float z = sigm_p(aZ.x + aZ.y);
    const float n = tanh_p((aNx.x + aNx.y) + r * (aNh.x + aNh.y));
    const float hnew = n + z * (h - n);
    h = (i >= istart) ? hnew : h;       // junk-suppress before layer's first step

    *pub = is_x ? xw : h;               // publish h (units) or x(i+1) (loaders)

    if (i >= 2) {                       // uniform branch
      if (is_o) *op = h;                // t = i-2, exec-masked
      op += ostep;
    }

    xw = xn;
    xn = xldv;
    __builtin_amdgcn_wave_barrier();    // keep next iter's reads after publishes
  }
}

extern "C" void kernel_launch(void* const* d_in, const int* in_sizes, int n_in,
                              void* d_out, int out_size, void* d_ws, size_t ws_size,
                              hipStream_t stream) {
  (void)in_sizes; (void)n_in; (void)d_ws; (void)ws_size; (void)out_size;
  const float* x     = (const float*)d_in[0];
  const float* w_ih0 = (const float*)d_in[1];
  const float* w_hh0 = (const float*)d_in[2];
  const float* b_ih0 = (const float*)d_in[3];
  const float* b_hh0 = (const float*)d_in[4];
  const float* w_ih1 = (const float*)d_in[5];
  const float* w_hh1 = (const float*)d_in[6];
  const float* b_ih1 = (const float*)d_in[7];
  const float* b_hh1 = (const float*)d_in[8];
  const float* w_ih2 = (const float*)d_in[9];
  const float* w_hh2 = (const float*)d_in[10];
  const float* b_ih2 = (const float*)d_in[11];
  const float* b_hh2 = (const float*)d_in[12];
  float* out = (float*)d_out;

  gru3_fused<<<NB / 2, 64, 0, stream>>>(
      x, w_ih0, w_hh0, b_ih0, b_hh0,
      w_ih1, w_hh1, b_ih1, b_hh1,
      w_ih2, w_hh2, b_ih2, b_hh2, out);
}

// Round 6
// 664.806 us; speedup vs baseline: 1.0202x; 1.0202x over previous
//
#include <hip/hip_runtime.h>

namespace {

constexpr int TT = 1024;   // timesteps
constexpr int NB = 4096;   // batch
constexpr int H0 = 15, H1 = 10, H2 = 2;

// Pre-scales so activations use v_exp_f32 (exp2) directly:
// sigmoid(v) = 1/(1+exp2(-v*L2E)); tanh(u) = 2/(1+exp2(-u*2*L2E)) - 1.
constexpr float L2E  = 1.44269504088896340736f;
constexpr float L2E2 = 2.88539008177792681472f;

// Staging vector per sample (floats): x[0..4] pad[5..7] h0[8..22] pad[23]
// h1[24..33] pad[34..35] h2[36..37] pad[38..47].  Window starts (16B-aligned):
// L0 -> 0 (x+h0), L1 -> 8 (h0+h1), L2 -> 24 (h1+h2). Window = 28 floats.
constexpr int SSTRIDE = 48;

typedef float v2f __attribute__((ext_vector_type(2)));
typedef float v4f __attribute__((ext_vector_type(4)));

__device__ __forceinline__ float frcp(float v)  { return __builtin_amdgcn_rcpf(v); }
__device__ __forceinline__ float fexp2(float v) { return __builtin_amdgcn_exp2f(v); }
__device__ __forceinline__ float sigm_p(float v) { return frcp(1.0f + fexp2(-v)); }
__device__ __forceinline__ float tanh_p(float u) {
  return __builtin_fmaf(2.0f, frcp(1.0f + fexp2(-u)), -1.0f);
}

// In-place packed FMA: acc = a*b + acc (single v_pk_fma_f32, acc tied).
__device__ __forceinline__ void pk_fma(v2f& acc, v2f a, v2f b) {
  asm("v_pk_fma_f32 %0, %1, %2, %0" : "+v"(acc) : "v"(a), "v"(b));
}
// Packed mul (chain head: kills acc-init movs, halves chain depth).
__device__ __forceinline__ v2f pk_mul(v2f a, v2f b) {
  v2f d;
  asm("v_pk_mul_f32 %0, %1, %2" : "=v"(d) : "v"(a), "v"(b));
  return d;
}

}  // namespace

// Grid: 2048 blocks x 64 threads = 2 waves/SIMD. Wave = 2 samples x 32 lanes.
// Per sample: lanes 0-14 = L0 units, 15-24 = L1 units, 25-26 = L2 units,
// 27-31 = x-loaders. Every lane reads a 28-float window of [x|h0|h1|h2]
// staging and does 4 zero-padded dots as 56 v_pk_fma/pk_mul, split into
// lo/hi half-chains (depth 7). Layers skewed (iter i: L0(i), L1(i-1),
// L2(i-2)) -> one publish/iteration. Single-wave block: no __syncthreads
// (wave-lockstep + in-order DS pipe); wave_barrier pins compiler ordering.
// x loads are pipelined 4-deep so the vmcnt wait has ~2 iterations of slack.
extern "C" __global__ __launch_bounds__(64, 2) void gru3_fused(
    const float* __restrict__ x,
    const float* __restrict__ w_ih0, const float* __restrict__ w_hh0,
    const float* __restrict__ b_ih0, const float* __restrict__ b_hh0,
    const float* __restrict__ w_ih1, const float* __restrict__ w_hh1,
    const float* __restrict__ b_ih1, const float* __restrict__ b_hh1,
    const float* __restrict__ w_ih2, const float* __restrict__ w_hh2,
    const float* __restrict__ b_ih2, const float* __restrict__ b_hh2,
    float* __restrict__ out) {
  // 2 samples * 48 + tail pad so L2's window over-read stays in-buffer.
  __shared__ __attribute__((aligned(16))) float stage[112];

  const int tid  = threadIdx.x;
  const int lane = tid & 31;
  const int smp  = tid >> 5;
  const int b    = blockIdx.x * 2 + smp;
  const int sbase = smp * SSTRIDE;

  int cls, u;
  if (lane < 15)      { cls = 0; u = lane; }
  else if (lane < 25) { cls = 1; u = lane - 15; }
  else if (lane < 27) { cls = 2; u = lane - 25; }
  else                { cls = 3; u = lane - 27; }   // x-loader

  const int  woff   = (cls == 0) ? 0 : (cls == 1) ? 8 : (cls == 2) ? 24 : 0;
  const int  wpos   = (cls == 0) ? 8 + u : (cls == 1) ? 24 + u
                    : (cls == 2) ? 36 + u : u;
  const int  istart = cls;            // suppress h-update until layer's first step
  const bool is_x   = (cls == 3);
  const bool is_o   = (cls == 2);
  const int  xj     = is_x ? u : 0;   // in-bounds x column for everyone

  // ---- per-lane padded weight vectors (zero outside class's inputs) ----
  float Wr[28], Wz[28], Wnx[28], Wnh[28];
#pragma unroll
  for (int j = 0; j < 28; ++j) { Wr[j] = 0.f; Wz[j] = 0.f; Wnx[j] = 0.f; Wnh[j] = 0.f; }
  float br = 0.f, bz = 0.f, bnx = 0.f, bnh = 0.f;

  if (cls == 0) {
#pragma unroll
    for (int j = 0; j < 5; ++j) {
      Wr [j] = w_ih0[(u         ) * 5 + j] * L2E;
      Wz [j] = w_ih0[(H0 + u    ) * 5 + j] * L2E;
      Wnx[j] = w_ih0[(2 * H0 + u) * 5 + j] * L2E2;
    }
#pragma unroll
    for (int k = 0; k < 15; ++k) {
      Wr [8 + k] = w_hh0[(u         ) * 15 + k] * L2E;
      Wz [8 + k] = w_hh0[(H0 + u    ) * 15 + k] * L2E;
      Wnh[8 + k] = w_hh0[(2 * H0 + u) * 15 + k] * L2E2;
    }
    br  = (b_ih0[u] + b_hh0[u]) * L2E;
    bz  = (b_ih0[H0 + u] + b_hh0[H0 + u]) * L2E;
    bnx = b_ih0[2 * H0 + u] * L2E2;
    bnh = b_hh0[2 * H0 + u] * L2E2;
  } else if (cls == 1) {
#pragma unroll
    for (int k = 0; k < 15; ++k) {
      Wr [k] = w_ih1[(u         ) * 15 + k] * L2E;
      Wz [k] = w_ih1[(H1 + u    ) * 15 + k] * L2E;
      Wnx[k] = w_ih1[(2 * H1 + u) * 15 + k] * L2E2;
    }
#pragma unroll
    for (int k = 0; k < 10; ++k) {
      Wr [16 + k] = w_hh1[(u         ) * 10 + k] * L2E;
      Wz [16 + k] = w_hh1[(H1 + u    ) * 10 + k] * L2E;
      Wnh[16 + k] = w_hh1[(2 * H1 + u) * 10 + k] * L2E2;
    }
    br  = (b_ih1[u] + b_hh1[u]) * L2E;
    bz  = (b_ih1[H1 + u] + b_hh1[H1 + u]) * L2E;
    bnx = b_ih1[2 * H1 + u] * L2E2;
    bnh = b_hh1[2 * H1 + u] * L2E2;
  } else if (cls == 2) {
#pragma unroll
    for (int k = 0; k < 10; ++k) {
      Wr [k] = w_ih2[(u         ) * 10 + k] * L2E;
      Wz [k] = w_ih2[(H2 + u    ) * 10 + k] * L2E;
      Wnx[k] = w_ih2[(2 * H2 + u) * 10 + k] * L2E2;
    }
#pragma unroll
    for (int k = 0; k < 2; ++k) {
      Wr [12 + k] = w_hh2[(u         ) * 2 + k] * L2E;
      Wz [12 + k] = w_hh2[(H2 + u    ) * 2 + k] * L2E;
      Wnh[12 + k] = w_hh2[(2 * H2 + u) * 2 + k] * L2E2;
    }
    br  = (b_ih2[u] + b_hh2[u]) * L2E;
    bz  = (b_ih2[H2 + u] + b_hh2[H2 + u]) * L2E;
    bnx = b_ih2[2 * H2 + u] * L2E2;
    bnh = b_hh2[2 * H2 + u] * L2E2;
  }

  // pack to float2 for v_pk_fma_f32
  v2f Wr2[14], Wz2[14], Wnx2[14], Wnh2[14];
#pragma unroll
  for (int j = 0; j < 14; ++j) {
    Wr2 [j] = (v2f){Wr [2 * j], Wr [2 * j + 1]};
    Wz2 [j] = (v2f){Wz [2 * j], Wz [2 * j + 1]};
    Wnx2[j] = (v2f){Wnx[2 * j], Wnx[2 * j + 1]};
    Wnh2[j] = (v2f){Wnh[2 * j], Wnh[2 * j + 1]};
  }

  // ---- init staging (zeros = h(-1) states + pads), publish x(0) ----
  for (int j = tid; j < 112; j += 64) stage[j] = 0.0f;

  // 4-deep x pipeline: xw = x(i+1) [published this iter], xn = x(i+2),
  // xf0 = x(i+3), xf1 = x(i+4); load targets x(i+5).
  float xw, xn, xf0, xf1;
  {
    const int base = b * 5 + xj;
    const float x0 = x[base];                       // t=0
    xw  = x[(size_t)1 * NB * 5 + base];             // t=1
    xn  = x[(size_t)2 * NB * 5 + base];             // t=2
    xf0 = x[(size_t)3 * NB * 5 + base];             // t=3
    xf1 = x[(size_t)4 * NB * 5 + base];             // t=4
    if (is_x) stage[sbase + u] = x0;
  }
  __builtin_amdgcn_wave_barrier();

  float h = 0.0f;
  const v4f* wloc = (const v4f*)&stage[sbase + woff];
  float* pub = &stage[sbase + wpos];

  // Strength-reduced pointers: x prefetch (x(i+5), clamped) and out store.
  const float* xp = x + ((size_t)5 * NB + b) * 5 + xj;
  const size_t xstep = (size_t)NB * 5;
  float* op = out + (size_t)b * H2 + (is_o ? u : 0);  // t = i-2 target
  const size_t ostep = (size_t)NB * H2;

#pragma unroll 2
  for (int i = 0; i <= TT + 1; ++i) {
    // window read (sees previous iteration's publishes; in-order DS pipe)
    const v4f q0 = wloc[0], q1 = wloc[1], q2 = wloc[2], q3 = wloc[3];
    const v4f q4 = wloc[4], q5 = wloc[5], q6 = wloc[6];

    // prefetch x(i+5); consumed 2 full iterations later -> vmcnt slack
    const float xldv = *xp;
    if (i + 6 < TT) xp += xstep;    // uniform scalar condition

    // lo/hi half-chains (depth 7), chain head = pk_mul (no acc init).
    v2f aRl  = pk_mul(Wr2 [0], q0.lo), aRh  = pk_mul(Wr2 [7], q3.hi);
    v2f aZl  = pk_mul(Wz2 [0], q0.lo), aZh  = pk_mul(Wz2 [7], q3.hi);
    v2f aNxl = pk_mul(Wnx2[0], q0.lo), aNxh = pk_mul(Wnx2[7], q3.hi);
    v2f aNhl = pk_mul(Wnh2[0], q0.lo), aNhh = pk_mul(Wnh2[7], q3.hi);
#define GRU_DOT2(J, QL, JH, QH)        \
    pk_fma(aRl,  Wr2 [J],  (QL));      \
    pk_fma(aZl,  Wz2 [J],  (QL));      \
    pk_fma(aNxl, Wnx2[J],  (QL));      \
    pk_fma(aNhl, Wnh2[J],  (QL));      \
    pk_fma(aRh,  Wr2 [JH], (QH));      \
    pk_fma(aZh,  Wz2 [JH], (QH));      \
    pk_fma(aNxh, Wnx2[JH], (QH));      \
    pk_fma(aNhh, Wnh2[JH], (QH));
    GRU_DOT2(1, q0.hi, 8,  q4.lo)
    GRU_DOT2(2, q1.lo, 9,  q4.hi)
    GRU_DOT2(3, q1.hi, 10, q5.lo)
    GRU_DOT2(4, q2.lo, 11, q5.hi)
    GRU_DOT2(5, q2.hi, 12, q6.lo)
    GRU_DOT2(6, q3.lo, 13, q6.hi)
#undef GRU_DOT2

    const float sR  = (aRl.x + aRl.y)   + (aRh.x + aRh.y)   + br;
    const float sZ  = (aZl.x + aZl.y)   + (aZh.x + aZh.y)   + bz;
    const float sNx = (aNxl.x + aNxl.y) + (aNxh.x + aNxh.y) + bnx;
    const float sNh = (aNhl.x + aNhl.y) + (aNhh.x + aNhh.y) + bnh;

    const float r = sigm_p(sR);
    const float z = sigm_p(sZ);
    const float n = tanh_p(sNx + r * sNh);
    const float hnew = n + z * (h - n);
    h = (i >= istart) ? hnew : h;       // junk-suppress before layer's first step

    *pub = is_x ? xw : h;               // publish h (units) or x(i+1) (loaders)

    if (i >= 2) {                       // uniform branch
      if (is_o) *op = h;                // t = i-2, exec-masked
      op += ostep;
    }

    xw  = xn;                           // rotate x pipeline (renamed by unroll)
    xn  = xf0;
    xf0 = xf1;
    xf1 = xldv;
    __builtin_amdgcn_wave_barrier();    // keep next iter's reads after publishes
  }
}

extern "C" void kernel_launch(void* const* d_in, const int* in_sizes, int n_in,
                              void* d_out, int out_size, void* d_ws, size_t ws_size,
                              hipStream_t stream) {
  (void)in_sizes; (void)n_in; (void)d_ws; (void)ws_size; (void)out_size;
  const float* x     = (const float*)d_in[0];
  const float* w_ih0 = (const float*)d_in[1];
  const float* w_hh0 = (const float*)d_in[2];
  const float* b_ih0 = (const float*)d_in[3];
  const float* b_hh0 = (const float*)d_in[4];
  const float* w_ih1 = (const float*)d_in[5];
  const float* w_hh1 = (const float*)d_in[6];
  const float* b_ih1 = (const float*)d_in[7];
  const float* b_hh1 = (const float*)d_in[8];
  const float* w_ih2 = (const float*)d_in[9];
  const float* w_hh2 = (const float*)d_in[10];
  const float* b_ih2 = (const float*)d_in[11];
  const float* b_hh2 = (const float*)d_in[12];
  float* out = (float*)d_out;

  gru3_fused<<<NB / 2, 64, 0, stream>>>(
      x, w_ih0, w_hh0, b_ih0, b_hh0,
      w_ih1, w_hh1, b_ih1, b_hh1,
      w_ih2, w_hh2, b_ih2, b_hh2, out);
}